// Round 4
// baseline (785.028 us; speedup 1.0000x reference)
//
#include <hip/hip_runtime.h>
#include <hip/hip_bf16.h>
#include <math.h>

#define NN 8192
// out = elu(0.5*h_s + (sum_j w_ij h_n_j)/Z_i), w_ij = adj_ij * max(es_i*en_j, 1)
// es = exp(s), en = exp(n): exp(relu(s+n)) == max(exp(s)*exp(n), 1)

typedef short short8 __attribute__((ext_vector_type(8)));   // 8 bf16 (4 VGPRs)
typedef float f32x4 __attribute__((ext_vector_type(4)));

__device__ __forceinline__ float eluf(float x) {
  return x > 0.f ? x : (__expf(x) - 1.f);
}
__device__ __forceinline__ unsigned short f2bf(float f) {
  union { float f; unsigned u; } v; v.f = f;
  unsigned r = v.u + 0x7fffu + ((v.u >> 16) & 1u);  // RNE
  return (unsigned short)(r >> 16);
}

// ---------------- Kernel 1: projections + fused exp(s)/exp(n) reductions ----------------
// 8 rows/block, block 256, grid 1024
__global__ __launch_bounds__(256) void k_proj(const float* __restrict__ X,
                                              const float* __restrict__ Ws,
                                              const float* __restrict__ Wn,
                                              const float* __restrict__ as_,
                                              const float* __restrict__ an_,
                                              float* __restrict__ Hs,
                                              unsigned short* __restrict__ HnT,
                                              float* __restrict__ es_out,
                                              float* __restrict__ en_out) {
  __shared__ float4 lin4[8 * 64];  // 8 rows x 256 f32 = 8 KB
  const int t = threadIdx.x;
  const int i0 = blockIdx.x * 8;
  const float4* Xg = (const float4*)X + (size_t)i0 * 64;
  lin4[t] = Xg[t];
  if (t < 256) lin4[t + 256] = Xg[t + 256];
  __syncthreads();
  const int c = t & 127;
  const int rh = t >> 7;  // 0..1, 4 rows each
  float accs[4], accn[4];
#pragma unroll
  for (int r = 0; r < 4; ++r) { accs[r] = 0.f; accn[r] = 0.f; }
  for (int k = 0; k < 256; k += 4) {
    float ws0 = Ws[(k + 0) * 128 + c], ws1 = Ws[(k + 1) * 128 + c];
    float ws2 = Ws[(k + 2) * 128 + c], ws3 = Ws[(k + 3) * 128 + c];
    float wn0 = Wn[(k + 0) * 128 + c], wn1 = Wn[(k + 1) * 128 + c];
    float wn2 = Wn[(k + 2) * 128 + c], wn3 = Wn[(k + 3) * 128 + c];
#pragma unroll
    for (int r = 0; r < 4; ++r) {
      float4 iv = lin4[(rh * 4 + r) * 64 + (k >> 2)];  // wave-uniform broadcast
      accs[r] = fmaf(iv.x, ws0, accs[r]); accs[r] = fmaf(iv.y, ws1, accs[r]);
      accs[r] = fmaf(iv.z, ws2, accs[r]); accs[r] = fmaf(iv.w, ws3, accs[r]);
      accn[r] = fmaf(iv.x, wn0, accn[r]); accn[r] = fmaf(iv.y, wn1, accn[r]);
      accn[r] = fmaf(iv.z, wn2, accn[r]); accn[r] = fmaf(iv.w, wn3, accn[r]);
    }
  }
#pragma unroll
  for (int r = 0; r < 4; ++r)
    Hs[(size_t)(i0 + rh * 4 + r) * 128 + c] = accs[r];
  {
    union { unsigned short us[4]; ushort4 u4; } pk;
#pragma unroll
    for (int r = 0; r < 4; ++r) pk.us[r] = f2bf(accn[r]);
    *(ushort4*)(HnT + (size_t)c * NN + i0 + rh * 4) = pk.u4;
  }
  // ---- fused reductions -> exp ----
  float* red = (float*)lin4;  // 8 x 128 f32
  const int wv = t >> 6, ln = t & 63;
  __syncthreads();
  {
    float av = as_[c];
#pragma unroll
    for (int r = 0; r < 4; ++r) red[(rh * 4 + r) * 128 + c] = accs[r] * av;
  }
  __syncthreads();
#pragma unroll
  for (int h = 0; h < 2; ++h) {
    int row = wv * 2 + h;
    float p = red[row * 128 + ln] + red[row * 128 + 64 + ln];
#pragma unroll
    for (int off = 32; off >= 1; off >>= 1) p += __shfl_down(p, off);
    if (ln == 0) es_out[i0 + row] = __expf(p);
  }
  __syncthreads();
  {
    float av = an_[c];
#pragma unroll
    for (int r = 0; r < 4; ++r) red[(rh * 4 + r) * 128 + c] = accn[r] * av;
  }
  __syncthreads();
#pragma unroll
  for (int h = 0; h < 2; ++h) {
    int row = wv * 2 + h;
    float p = red[row * 128 + ln] + red[row * 128 + 64 + ln];
#pragma unroll
    for (int off = 32; off >= 1; off >>= 1) p += __shfl_down(p, off);
    if (ln == 0) en_out[i0 + row] = __expf(p);
  }
}

// ---------------- Kernel 2: fused attention GEMM, barrier-free K-loop ----------------
// 16 rows/block, block 256 (4 independent waves), grid 512. j-tiles of 128.
// Each wave: 16 rows x 32 f-cols (2 f-tiles), computes its OWN A-frags for all 4
// K-steps (adj redundancy absorbed by L1). No LDS, no __syncthreads in the loop ->
// no vmcnt(0) drain; register FIFO keeps adj ~1.2 tiles in flight continuously.
__global__ __launch_bounds__(256, 2) void k_main(const int* __restrict__ A,
                                                 const unsigned short* __restrict__ HnT,
                                                 const float* __restrict__ es_g,
                                                 const float* __restrict__ en_g,
                                                 float* __restrict__ HsOut) {
  const int t = threadIdx.x;
  const int wv = t >> 6;
  const int ln = t & 63;
  const int q = ln >> 4;   // quad
  const int m = ln & 15;   // A row / C col
  const int row0 = blockIdx.x * 16;

  const float es = es_g[row0 + m];
  const int* aptr = A + (size_t)(row0 + m) * NN + q * 8;
  const float* nptr = en_g + q * 8;
  const int f0 = wv * 32 + m;
  const unsigned short* bb0 = HnT + (size_t)f0 * NN + q * 8;
  const unsigned short* bb1 = HnT + (size_t)(f0 + 16) * NN + q * 8;

  f32x4 acc0 = {0.f, 0.f, 0.f, 0.f}, acc1 = {0.f, 0.f, 0.f, 0.f};
  float zp = 0.f;

  int4 adjv[2][4][2];    // [buf][ks][half]
  float4 env[2][4][2];
  union BU { uint4 u; short8 s; } breg[8];

  // prolog (FIFO oldest-first): adj(0), en(0), adj(1), en(1), B(0)
#pragma unroll
  for (int ks = 0; ks < 4; ++ks) {
    adjv[0][ks][0] = *(const int4*)(aptr + ks * 32);
    adjv[0][ks][1] = *(const int4*)(aptr + ks * 32 + 4);
  }
#pragma unroll
  for (int ks = 0; ks < 4; ++ks) {
    env[0][ks][0] = *(const float4*)(nptr + ks * 32);
    env[0][ks][1] = *(const float4*)(nptr + ks * 32 + 4);
  }
#pragma unroll
  for (int ks = 0; ks < 4; ++ks) {
    adjv[1][ks][0] = *(const int4*)(aptr + 128 + ks * 32);
    adjv[1][ks][1] = *(const int4*)(aptr + 128 + ks * 32 + 4);
  }
#pragma unroll
  for (int ks = 0; ks < 4; ++ks) {
    env[1][ks][0] = *(const float4*)(nptr + 128 + ks * 32);
    env[1][ks][1] = *(const float4*)(nptr + 128 + ks * 32 + 4);
  }
#pragma unroll
  for (int ks = 0; ks < 4; ++ks) {
    breg[ks].u     = *(const uint4*)(bb0 + ks * 32);
    breg[4 + ks].u = *(const uint4*)(bb1 + ks * 32);
  }

#pragma unroll 2
  for (int tt = 0; tt < 64; ++tt) {
    const int cur = tt & 1;
    // ---- build A-frags for tile tt from regs (already landed; no drain needed) ----
    short8 afr[4];
#pragma unroll
    for (int ks = 0; ks < 4; ++ks) {
      const int4 a0 = adjv[cur][ks][0], a1 = adjv[cur][ks][1];
      const float4 e0 = env[cur][ks][0], e1 = env[cur][ks][1];
      float w0 = a0.x > 0 ? fmaxf(es * e0.x, 1.f) : 0.f;
      float w1 = a0.y > 0 ? fmaxf(es * e0.y, 1.f) : 0.f;
      float w2 = a0.z > 0 ? fmaxf(es * e0.z, 1.f) : 0.f;
      float w3 = a0.w > 0 ? fmaxf(es * e0.w, 1.f) : 0.f;
      float w4 = a1.x > 0 ? fmaxf(es * e1.x, 1.f) : 0.f;
      float w5 = a1.y > 0 ? fmaxf(es * e1.y, 1.f) : 0.f;
      float w6 = a1.z > 0 ? fmaxf(es * e1.z, 1.f) : 0.f;
      float w7 = a1.w > 0 ? fmaxf(es * e1.w, 1.f) : 0.f;
      zp += ((w0 + w1) + (w2 + w3)) + ((w4 + w5) + (w6 + w7));
      __hip_bfloat162 p01 = __float22bfloat162_rn(float2{w0, w1});
      __hip_bfloat162 p23 = __float22bfloat162_rn(float2{w2, w3});
      __hip_bfloat162 p45 = __float22bfloat162_rn(float2{w4, w5});
      __hip_bfloat162 p67 = __float22bfloat162_rn(float2{w6, w7});
      union { unsigned u[4]; short8 s; } fr;
      fr.u[0] = *(unsigned*)&p01; fr.u[1] = *(unsigned*)&p23;
      fr.u[2] = *(unsigned*)&p45; fr.u[3] = *(unsigned*)&p67;
      afr[ks] = fr.s;
    }
    // ---- issue adj(tt+2), en(tt+2) into the consumed buffer ----
    if (tt < 62) {
      const int* ap = aptr + (size_t)(tt + 2) * 128;
      const float* np = nptr + (size_t)(tt + 2) * 128;
#pragma unroll
      for (int ks = 0; ks < 4; ++ks) {
        adjv[cur][ks][0] = *(const int4*)(ap + ks * 32);
        adjv[cur][ks][1] = *(const int4*)(ap + ks * 32 + 4);
      }
#pragma unroll
      for (int ks = 0; ks < 4; ++ks) {
        env[cur][ks][0] = *(const float4*)(np + ks * 32);
        env[cur][ks][1] = *(const float4*)(np + ks * 32 + 4);
      }
    }
    // ---- MFMA on B(tt): waits vmcnt(16) -> adj/en(tt+2) stay in flight ----
    acc0 = __builtin_amdgcn_mfma_f32_16x16x32_bf16(afr[0], breg[0].s, acc0, 0, 0, 0);
    acc1 = __builtin_amdgcn_mfma_f32_16x16x32_bf16(afr[0], breg[4].s, acc1, 0, 0, 0);
    acc0 = __builtin_amdgcn_mfma_f32_16x16x32_bf16(afr[1], breg[1].s, acc0, 0, 0, 0);
    acc1 = __builtin_amdgcn_mfma_f32_16x16x32_bf16(afr[1], breg[5].s, acc1, 0, 0, 0);
    acc0 = __builtin_amdgcn_mfma_f32_16x16x32_bf16(afr[2], breg[2].s, acc0, 0, 0, 0);
    acc1 = __builtin_amdgcn_mfma_f32_16x16x32_bf16(afr[2], breg[6].s, acc1, 0, 0, 0);
    acc0 = __builtin_amdgcn_mfma_f32_16x16x32_bf16(afr[3], breg[3].s, acc0, 0, 0, 0);
    acc1 = __builtin_amdgcn_mfma_f32_16x16x32_bf16(afr[3], breg[7].s, acc1, 0, 0, 0);
    // ---- issue B(tt+1) (newest in FIFO) ----
    if (tt < 63) {
      const size_t jt = (size_t)(tt + 1) * 128;
#pragma unroll
      for (int ks = 0; ks < 4; ++ks) {
        breg[ks].u     = *(const uint4*)(bb0 + jt + ks * 32);
        breg[4 + ks].u = *(const uint4*)(bb1 + jt + ks * 32);
      }
    }
  }

  // ---- Z: in-wave butterfly across q (lanes share m at ln = q*16+m) ----
  float zz = zp;
  zz += __shfl_xor(zz, 16);
  zz += __shfl_xor(zz, 32);           // every lane now holds Z[m] for its m
  const float invz = 1.f / zz;

  // ---- epilogue: out = elu(0.5*h_s + acc/Z); C-layout col=m, row=q*4+reg ----
#pragma unroll
  for (int reg = 0; reg < 4; ++reg) {
    const int row = q * 4 + reg;
    const float iz = __shfl(invz, row);  // lane 'row' has m==row
    const size_t off = (size_t)(row0 + row) * 128 + f0;
    float h0 = HsOut[off], h1 = HsOut[off + 16];
    HsOut[off]      = eluf(fmaf(acc0[reg], iz, 0.5f * h0));
    HsOut[off + 16] = eluf(fmaf(acc1[reg], iz, 0.5f * h1));
  }
}

extern "C" void kernel_launch(void* const* d_in, const int* in_sizes, int n_in,
                              void* d_out, int out_size, void* d_ws, size_t ws_size,
                              hipStream_t stream) {
  const float* X   = (const float*)d_in[0];
  const int*   A   = (const int*)d_in[1];
  const float* Ws  = (const float*)d_in[2];
  const float* as_ = (const float*)d_in[3];
  const float* Wn  = (const float*)d_in[4];
  const float* an_ = (const float*)d_in[5];
  float* out = (float*)d_out;  // holds h_s, then final output (in-place epilogue)

  unsigned short* HnT = (unsigned short*)d_ws;       // 128*8192 bf16 = 2 MB
  float* es = (float*)(HnT + (size_t)128 * NN);      // 8192 f32 (= exp(s))
  float* en = es + NN;                               // 8192 f32 (= exp(n))

  k_proj<<<1024, 256, 0, stream>>>(X, Ws, Wn, as_, an_, out, HnT, es, en);
  k_main<<<512, 256, 0, stream>>>(A, HnT, es, en, out);
}

// Round 5
// 716.752 us; speedup vs baseline: 1.0953x; 1.0953x over previous
//
#include <hip/hip_runtime.h>
#include <hip/hip_bf16.h>
#include <math.h>

#define NN 8192
// out = elu(0.5*h_s + (sum_j w_ij h_n_j)/Z_i), w_ij = adj_ij * max(es_i*en_j, 1)
// es = exp(s), en = exp(n): exp(relu(s+n)) == max(exp(s)*exp(n), 1)

typedef short short8 __attribute__((ext_vector_type(8)));   // 8 bf16 (4 VGPRs)
typedef float f32x4 __attribute__((ext_vector_type(4)));

__device__ __forceinline__ float eluf(float x) {
  return x > 0.f ? x : (__expf(x) - 1.f);
}
__device__ __forceinline__ unsigned short f2bf(float f) {
  union { float f; unsigned u; } v; v.f = f;
  unsigned r = v.u + 0x7fffu + ((v.u >> 16) & 1u);  // RNE
  return (unsigned short)(r >> 16);
}

// ---------------- Kernel 1: projections + fused exp(s)/exp(n) reductions ----------------
// 8 rows/block, block 256, grid 1024
__global__ __launch_bounds__(256) void k_proj(const float* __restrict__ X,
                                              const float* __restrict__ Ws,
                                              const float* __restrict__ Wn,
                                              const float* __restrict__ as_,
                                              const float* __restrict__ an_,
                                              float* __restrict__ Hs,
                                              unsigned short* __restrict__ HnT,
                                              float* __restrict__ es_out,
                                              float* __restrict__ en_out) {
  __shared__ float4 lin4[8 * 64];  // 8 rows x 256 f32 = 8 KB
  const int t = threadIdx.x;
  const int i0 = blockIdx.x * 8;
  const float4* Xg = (const float4*)X + (size_t)i0 * 64;
  lin4[t] = Xg[t];
  if (t < 256) lin4[t + 256] = Xg[t + 256];
  __syncthreads();
  const int c = t & 127;
  const int rh = t >> 7;  // 0..1, 4 rows each
  float accs[4], accn[4];
#pragma unroll
  for (int r = 0; r < 4; ++r) { accs[r] = 0.f; accn[r] = 0.f; }
  for (int k = 0; k < 256; k += 4) {
    float ws0 = Ws[(k + 0) * 128 + c], ws1 = Ws[(k + 1) * 128 + c];
    float ws2 = Ws[(k + 2) * 128 + c], ws3 = Ws[(k + 3) * 128 + c];
    float wn0 = Wn[(k + 0) * 128 + c], wn1 = Wn[(k + 1) * 128 + c];
    float wn2 = Wn[(k + 2) * 128 + c], wn3 = Wn[(k + 3) * 128 + c];
#pragma unroll
    for (int r = 0; r < 4; ++r) {
      float4 iv = lin4[(rh * 4 + r) * 64 + (k >> 2)];  // wave-uniform broadcast
      accs[r] = fmaf(iv.x, ws0, accs[r]); accs[r] = fmaf(iv.y, ws1, accs[r]);
      accs[r] = fmaf(iv.z, ws2, accs[r]); accs[r] = fmaf(iv.w, ws3, accs[r]);
      accn[r] = fmaf(iv.x, wn0, accn[r]); accn[r] = fmaf(iv.y, wn1, accn[r]);
      accn[r] = fmaf(iv.z, wn2, accn[r]); accn[r] = fmaf(iv.w, wn3, accn[r]);
    }
  }
#pragma unroll
  for (int r = 0; r < 4; ++r)
    Hs[(size_t)(i0 + rh * 4 + r) * 128 + c] = accs[r];
  {
    union { unsigned short us[4]; ushort4 u4; } pk;
#pragma unroll
    for (int r = 0; r < 4; ++r) pk.us[r] = f2bf(accn[r]);
    *(ushort4*)(HnT + (size_t)c * NN + i0 + rh * 4) = pk.u4;
  }
  // ---- fused reductions -> exp ----
  float* red = (float*)lin4;  // 8 x 128 f32
  const int wv = t >> 6, ln = t & 63;
  __syncthreads();
  {
    float av = as_[c];
#pragma unroll
    for (int r = 0; r < 4; ++r) red[(rh * 4 + r) * 128 + c] = accs[r] * av;
  }
  __syncthreads();
#pragma unroll
  for (int h = 0; h < 2; ++h) {
    int row = wv * 2 + h;
    float p = red[row * 128 + ln] + red[row * 128 + 64 + ln];
#pragma unroll
    for (int off = 32; off >= 1; off >>= 1) p += __shfl_down(p, off);
    if (ln == 0) es_out[i0 + row] = __expf(p);
  }
  __syncthreads();
  {
    float av = an_[c];
#pragma unroll
    for (int r = 0; r < 4; ++r) red[(rh * 4 + r) * 128 + c] = accn[r] * av;
  }
  __syncthreads();
#pragma unroll
  for (int h = 0; h < 2; ++h) {
    int row = wv * 2 + h;
    float p = red[row * 128 + ln] + red[row * 128 + 64 + ln];
#pragma unroll
    for (int off = 32; off >= 1; off >>= 1) p += __shfl_down(p, off);
    if (ln == 0) en_out[i0 + row] = __expf(p);
  }
}

// ---------------- Kernel 2: fused attention GEMM, barrier-free K-loop ----------------
// 16 rows/block, block 256 (4 independent waves), grid 512. j-tiles of 128.
// All prefetch buffers are NAMED variables + manually unrolled x2 body -> the
// compiler cannot demote them to scratch (R4's 603 MB WRITE_SIZE bug).
__device__ __forceinline__ short8 mk_frag(int4 a0, int4 a1, float4 e0, float4 e1,
                                          float es, float& zp) {
  float w0 = a0.x > 0 ? fmaxf(es * e0.x, 1.f) : 0.f;
  float w1 = a0.y > 0 ? fmaxf(es * e0.y, 1.f) : 0.f;
  float w2 = a0.z > 0 ? fmaxf(es * e0.z, 1.f) : 0.f;
  float w3 = a0.w > 0 ? fmaxf(es * e0.w, 1.f) : 0.f;
  float w4 = a1.x > 0 ? fmaxf(es * e1.x, 1.f) : 0.f;
  float w5 = a1.y > 0 ? fmaxf(es * e1.y, 1.f) : 0.f;
  float w6 = a1.z > 0 ? fmaxf(es * e1.z, 1.f) : 0.f;
  float w7 = a1.w > 0 ? fmaxf(es * e1.w, 1.f) : 0.f;
  zp += ((w0 + w1) + (w2 + w3)) + ((w4 + w5) + (w6 + w7));
  __hip_bfloat162 p01 = __float22bfloat162_rn(float2{w0, w1});
  __hip_bfloat162 p23 = __float22bfloat162_rn(float2{w2, w3});
  __hip_bfloat162 p45 = __float22bfloat162_rn(float2{w4, w5});
  __hip_bfloat162 p67 = __float22bfloat162_rn(float2{w6, w7});
  union { unsigned u[4]; short8 s; } fr;
  fr.u[0] = *(unsigned*)&p01; fr.u[1] = *(unsigned*)&p23;
  fr.u[2] = *(unsigned*)&p45; fr.u[3] = *(unsigned*)&p67;
  return fr.s;
}

// one tile body: consume ADJ/ENV(tt) -> prefetch ADJ/ENV(tt+2) -> MFMA B(tt) -> load B(tt+1)
#define GAT_BODY(tt, ADJ, ENV)                                                  \
  {                                                                             \
    short8 afr0 = mk_frag(ADJ##0a, ADJ##0b, ENV##0a, ENV##0b, es, zp);          \
    short8 afr1 = mk_frag(ADJ##1a, ADJ##1b, ENV##1a, ENV##1b, es, zp);          \
    short8 afr2 = mk_frag(ADJ##2a, ADJ##2b, ENV##2a, ENV##2b, es, zp);          \
    short8 afr3 = mk_frag(ADJ##3a, ADJ##3b, ENV##3a, ENV##3b, es, zp);          \
    if ((tt) < 62) {                                                            \
      const int* ap = aptr + (size_t)((tt) + 2) * 128;                          \
      const float* np = nptr + (size_t)((tt) + 2) * 128;                        \
      ADJ##0a = *(const int4*)(ap);       ADJ##0b = *(const int4*)(ap + 4);     \
      ADJ##1a = *(const int4*)(ap + 32);  ADJ##1b = *(const int4*)(ap + 36);    \
      ADJ##2a = *(const int4*)(ap + 64);  ADJ##2b = *(const int4*)(ap + 68);    \
      ADJ##3a = *(const int4*)(ap + 96);  ADJ##3b = *(const int4*)(ap + 100);   \
      ENV##0a = *(const float4*)(np);      ENV##0b = *(const float4*)(np + 4);  \
      ENV##1a = *(const float4*)(np + 32); ENV##1b = *(const float4*)(np + 36); \
      ENV##2a = *(const float4*)(np + 64); ENV##2b = *(const float4*)(np + 68); \
      ENV##3a = *(const float4*)(np + 96); ENV##3b = *(const float4*)(np + 100);\
    }                                                                           \
    acc0 = __builtin_amdgcn_mfma_f32_16x16x32_bf16(afr0, b0.s, acc0, 0, 0, 0);  \
    acc1 = __builtin_amdgcn_mfma_f32_16x16x32_bf16(afr0, b4.s, acc1, 0, 0, 0);  \
    acc0 = __builtin_amdgcn_mfma_f32_16x16x32_bf16(afr1, b1.s, acc0, 0, 0, 0);  \
    acc1 = __builtin_amdgcn_mfma_f32_16x16x32_bf16(afr1, b5.s, acc1, 0, 0, 0);  \
    acc0 = __builtin_amdgcn_mfma_f32_16x16x32_bf16(afr2, b2.s, acc0, 0, 0, 0);  \
    acc1 = __builtin_amdgcn_mfma_f32_16x16x32_bf16(afr2, b6.s, acc1, 0, 0, 0);  \
    acc0 = __builtin_amdgcn_mfma_f32_16x16x32_bf16(afr3, b3.s, acc0, 0, 0, 0);  \
    acc1 = __builtin_amdgcn_mfma_f32_16x16x32_bf16(afr3, b7.s, acc1, 0, 0, 0);  \
    if ((tt) < 63) {                                                            \
      const size_t jt = (size_t)((tt) + 1) * 128;                               \
      b0.u = *(const uint4*)(bb0 + jt);      b1.u = *(const uint4*)(bb0 + jt + 32); \
      b2.u = *(const uint4*)(bb0 + jt + 64); b3.u = *(const uint4*)(bb0 + jt + 96); \
      b4.u = *(const uint4*)(bb1 + jt);      b5.u = *(const uint4*)(bb1 + jt + 32); \
      b6.u = *(const uint4*)(bb1 + jt + 64); b7.u = *(const uint4*)(bb1 + jt + 96); \
    }                                                                           \
  }

__global__ __launch_bounds__(256, 2) void k_main(const int* __restrict__ A,
                                                 const unsigned short* __restrict__ HnT,
                                                 const float* __restrict__ es_g,
                                                 const float* __restrict__ en_g,
                                                 float* __restrict__ HsOut) {
  const int t = threadIdx.x;
  const int wv = t >> 6;
  const int ln = t & 63;
  const int q = ln >> 4;   // quad
  const int m = ln & 15;   // A row / C col
  const int row0 = blockIdx.x * 16;

  const float es = es_g[row0 + m];
  const int* aptr = A + (size_t)(row0 + m) * NN + q * 8;
  const float* nptr = en_g + q * 8;
  const int f0 = wv * 32 + m;
  const unsigned short* bb0 = HnT + (size_t)f0 * NN + q * 8;
  const unsigned short* bb1 = HnT + (size_t)(f0 + 16) * NN + q * 8;

  f32x4 acc0 = {0.f, 0.f, 0.f, 0.f}, acc1 = {0.f, 0.f, 0.f, 0.f};
  float zp = 0.f;

  // named prefetch registers (even tiles = A-set, odd tiles = B-set)
  int4 adjA0a, adjA0b, adjA1a, adjA1b, adjA2a, adjA2b, adjA3a, adjA3b;
  int4 adjB0a, adjB0b, adjB1a, adjB1b, adjB2a, adjB2b, adjB3a, adjB3b;
  float4 envA0a, envA0b, envA1a, envA1b, envA2a, envA2b, envA3a, envA3b;
  float4 envB0a, envB0b, envB1a, envB1b, envB2a, envB2b, envB3a, envB3b;
  union BU { uint4 u; short8 s; } b0, b1, b2, b3, b4, b5, b6, b7;

  // prolog (FIFO oldest-first): adj(0), env(0), adj(1), env(1), B(0)
  adjA0a = *(const int4*)(aptr);       adjA0b = *(const int4*)(aptr + 4);
  adjA1a = *(const int4*)(aptr + 32);  adjA1b = *(const int4*)(aptr + 36);
  adjA2a = *(const int4*)(aptr + 64);  adjA2b = *(const int4*)(aptr + 68);
  adjA3a = *(const int4*)(aptr + 96);  adjA3b = *(const int4*)(aptr + 100);
  envA0a = *(const float4*)(nptr);      envA0b = *(const float4*)(nptr + 4);
  envA1a = *(const float4*)(nptr + 32); envA1b = *(const float4*)(nptr + 36);
  envA2a = *(const float4*)(nptr + 64); envA2b = *(const float4*)(nptr + 68);
  envA3a = *(const float4*)(nptr + 96); envA3b = *(const float4*)(nptr + 100);
  adjB0a = *(const int4*)(aptr + 128);  adjB0b = *(const int4*)(aptr + 132);
  adjB1a = *(const int4*)(aptr + 160);  adjB1b = *(const int4*)(aptr + 164);
  adjB2a = *(const int4*)(aptr + 192);  adjB2b = *(const int4*)(aptr + 196);
  adjB3a = *(const int4*)(aptr + 224);  adjB3b = *(const int4*)(aptr + 228);
  envB0a = *(const float4*)(nptr + 128); envB0b = *(const float4*)(nptr + 132);
  envB1a = *(const float4*)(nptr + 160); envB1b = *(const float4*)(nptr + 164);
  envB2a = *(const float4*)(nptr + 192); envB2b = *(const float4*)(nptr + 196);
  envB3a = *(const float4*)(nptr + 224); envB3b = *(const float4*)(nptr + 228);
  b0.u = *(const uint4*)(bb0);      b1.u = *(const uint4*)(bb0 + 32);
  b2.u = *(const uint4*)(bb0 + 64); b3.u = *(const uint4*)(bb0 + 96);
  b4.u = *(const uint4*)(bb1);      b5.u = *(const uint4*)(bb1 + 32);
  b6.u = *(const uint4*)(bb1 + 64); b7.u = *(const uint4*)(bb1 + 96);

  for (int tt = 0; tt < 64; tt += 2) {
    GAT_BODY(tt, adjA, envA)
    GAT_BODY(tt + 1, adjB, envB)
  }

  // ---- Z: in-wave butterfly across q (lanes share m at ln = q*16+m) ----
  float zz = zp;
  zz += __shfl_xor(zz, 16);
  zz += __shfl_xor(zz, 32);           // every lane now holds Z[m] for its m
  const float invz = 1.f / zz;

  // ---- epilogue: out = elu(0.5*h_s + acc/Z); C-layout col=m, row=q*4+reg ----
#pragma unroll
  for (int reg = 0; reg < 4; ++reg) {
    const int row = q * 4 + reg;
    const float iz = __shfl(invz, row);  // lane 'row' has m==row
    const size_t off = (size_t)(row0 + row) * 128 + f0;
    float h0 = HsOut[off], h1 = HsOut[off + 16];
    HsOut[off]      = eluf(fmaf(acc0[reg], iz, 0.5f * h0));
    HsOut[off + 16] = eluf(fmaf(acc1[reg], iz, 0.5f * h1));
  }
}

extern "C" void kernel_launch(void* const* d_in, const int* in_sizes, int n_in,
                              void* d_out, int out_size, void* d_ws, size_t ws_size,
                              hipStream_t stream) {
  const float* X   = (const float*)d_in[0];
  const int*   A   = (const int*)d_in[1];
  const float* Ws  = (const float*)d_in[2];
  const float* as_ = (const float*)d_in[3];
  const float* Wn  = (const float*)d_in[4];
  const float* an_ = (const float*)d_in[5];
  float* out = (float*)d_out;  // holds h_s, then final output (in-place epilogue)

  unsigned short* HnT = (unsigned short*)d_ws;       // 128*8192 bf16 = 2 MB
  float* es = (float*)(HnT + (size_t)128 * NN);      // 8192 f32 (= exp(s))
  float* en = es + NN;                               // 8192 f32 (= exp(n))

  k_proj<<<1024, 256, 0, stream>>>(X, Ws, Wn, as_, an_, out, HnT, es, en);
  k_main<<<512, 256, 0, stream>>>(A, HnT, es, en, out);
}

// Round 6
// 562.557 us; speedup vs baseline: 1.3955x; 1.2741x over previous
//
#include <hip/hip_runtime.h>
#include <hip/hip_bf16.h>
#include <math.h>

#define NN 8192
// out = elu(0.5*h_s + (sum_j w_ij h_n_j)/Z_i), w_ij = adj_ij * max(es_i*en_j, 1)
// es = exp(s), en = exp(n): exp(relu(s+n)) == max(exp(s)*exp(n), 1)

typedef short short8 __attribute__((ext_vector_type(8)));   // 8 bf16 (4 VGPRs)
typedef float f32x4 __attribute__((ext_vector_type(4)));

__device__ __forceinline__ float eluf(float x) {
  return x > 0.f ? x : (__expf(x) - 1.f);
}
__device__ __forceinline__ unsigned short f2bf(float f) {
  union { float f; unsigned u; } v; v.f = f;
  unsigned r = v.u + 0x7fffu + ((v.u >> 16) & 1u);  // RNE
  return (unsigned short)(r >> 16);
}

// ---------------- Kernel 1: projections + fused exp(s)/exp(n) reductions ----------------
// 8 rows/block, block 256, grid 1024
__global__ __launch_bounds__(256) void k_proj(const float* __restrict__ X,
                                              const float* __restrict__ Ws,
                                              const float* __restrict__ Wn,
                                              const float* __restrict__ as_,
                                              const float* __restrict__ an_,
                                              float* __restrict__ Hs,
                                              unsigned short* __restrict__ HnT,
                                              float* __restrict__ es_out,
                                              float* __restrict__ en_out) {
  __shared__ float4 lin4[8 * 64];  // 8 rows x 256 f32 = 8 KB
  const int t = threadIdx.x;
  const int i0 = blockIdx.x * 8;
  const float4* Xg = (const float4*)X + (size_t)i0 * 64;
  lin4[t] = Xg[t];
  if (t < 256) lin4[t + 256] = Xg[t + 256];
  __syncthreads();
  const int c = t & 127;
  const int rh = t >> 7;  // 0..1, 4 rows each
  float accs[4], accn[4];
#pragma unroll
  for (int r = 0; r < 4; ++r) { accs[r] = 0.f; accn[r] = 0.f; }
  for (int k = 0; k < 256; k += 4) {
    float ws0 = Ws[(k + 0) * 128 + c], ws1 = Ws[(k + 1) * 128 + c];
    float ws2 = Ws[(k + 2) * 128 + c], ws3 = Ws[(k + 3) * 128 + c];
    float wn0 = Wn[(k + 0) * 128 + c], wn1 = Wn[(k + 1) * 128 + c];
    float wn2 = Wn[(k + 2) * 128 + c], wn3 = Wn[(k + 3) * 128 + c];
#pragma unroll
    for (int r = 0; r < 4; ++r) {
      float4 iv = lin4[(rh * 4 + r) * 64 + (k >> 2)];  // wave-uniform broadcast
      accs[r] = fmaf(iv.x, ws0, accs[r]); accs[r] = fmaf(iv.y, ws1, accs[r]);
      accs[r] = fmaf(iv.z, ws2, accs[r]); accs[r] = fmaf(iv.w, ws3, accs[r]);
      accn[r] = fmaf(iv.x, wn0, accn[r]); accn[r] = fmaf(iv.y, wn1, accn[r]);
      accn[r] = fmaf(iv.z, wn2, accn[r]); accn[r] = fmaf(iv.w, wn3, accn[r]);
    }
  }
#pragma unroll
  for (int r = 0; r < 4; ++r)
    Hs[(size_t)(i0 + rh * 4 + r) * 128 + c] = accs[r];
  {
    union { unsigned short us[4]; ushort4 u4; } pk;
#pragma unroll
    for (int r = 0; r < 4; ++r) pk.us[r] = f2bf(accn[r]);
    *(ushort4*)(HnT + (size_t)c * NN + i0 + rh * 4) = pk.u4;
  }
  // ---- fused reductions -> exp ----
  float* red = (float*)lin4;  // 8 x 128 f32
  const int wv = t >> 6, ln = t & 63;
  __syncthreads();
  {
    float av = as_[c];
#pragma unroll
    for (int r = 0; r < 4; ++r) red[(rh * 4 + r) * 128 + c] = accs[r] * av;
  }
  __syncthreads();
#pragma unroll
  for (int h = 0; h < 2; ++h) {
    int row = wv * 2 + h;
    float p = red[row * 128 + ln] + red[row * 128 + 64 + ln];
#pragma unroll
    for (int off = 32; off >= 1; off >>= 1) p += __shfl_down(p, off);
    if (ln == 0) es_out[i0 + row] = __expf(p);
  }
  __syncthreads();
  {
    float av = an_[c];
#pragma unroll
    for (int r = 0; r < 4; ++r) red[(rh * 4 + r) * 128 + c] = accn[r] * av;
  }
  __syncthreads();
#pragma unroll
  for (int h = 0; h < 2; ++h) {
    int row = wv * 2 + h;
    float p = red[row * 128 + ln] + red[row * 128 + 64 + ln];
#pragma unroll
    for (int off = 32; off >= 1; off >>= 1) p += __shfl_down(p, off);
    if (ln == 0) en_out[i0 + row] = __expf(p);
  }
}

// ---------------- Kernel 2: fused attention GEMM, barrier-free K-loop ----------------
// 16 rows/block, block 256 (4 independent waves), grid 512. j-tiles of 128.
// amdgpu_waves_per_eu(2,2) pins occupancy to 2 waves/EU -> 256-VGPR budget, so
// the named prefetch registers CANNOT be spilled (R4/R5: backend targeted 4
// waves/EU, capped at 128 VGPRs, spilled 300+ MB to scratch).
__device__ __forceinline__ short8 mk_frag(int4 a0, int4 a1, float4 e0, float4 e1,
                                          float es, float& zp) {
  float w0 = a0.x > 0 ? fmaxf(es * e0.x, 1.f) : 0.f;
  float w1 = a0.y > 0 ? fmaxf(es * e0.y, 1.f) : 0.f;
  float w2 = a0.z > 0 ? fmaxf(es * e0.z, 1.f) : 0.f;
  float w3 = a0.w > 0 ? fmaxf(es * e0.w, 1.f) : 0.f;
  float w4 = a1.x > 0 ? fmaxf(es * e1.x, 1.f) : 0.f;
  float w5 = a1.y > 0 ? fmaxf(es * e1.y, 1.f) : 0.f;
  float w6 = a1.z > 0 ? fmaxf(es * e1.z, 1.f) : 0.f;
  float w7 = a1.w > 0 ? fmaxf(es * e1.w, 1.f) : 0.f;
  zp += ((w0 + w1) + (w2 + w3)) + ((w4 + w5) + (w6 + w7));
  __hip_bfloat162 p01 = __float22bfloat162_rn(float2{w0, w1});
  __hip_bfloat162 p23 = __float22bfloat162_rn(float2{w2, w3});
  __hip_bfloat162 p45 = __float22bfloat162_rn(float2{w4, w5});
  __hip_bfloat162 p67 = __float22bfloat162_rn(float2{w6, w7});
  union { unsigned u[4]; short8 s; } fr;
  fr.u[0] = *(unsigned*)&p01; fr.u[1] = *(unsigned*)&p23;
  fr.u[2] = *(unsigned*)&p45; fr.u[3] = *(unsigned*)&p67;
  return fr.s;
}

// one tile body: consume ADJ(tt)+env -> reissue env(tt+1) -> prefetch ADJ(tt+2)
// -> MFMA B(tt) -> load B(tt+1). env is single-buffered (L1-hot; lands a full
// body before next consumption). FIFO: waiting B(tt) leaves env(tt+1)+adj(tt+2)
// in flight; adj (the HBM stream) is never drained.
#define GAT_BODY(tt, ADJ)                                                       \
  {                                                                             \
    short8 afr0 = mk_frag(ADJ##0a, ADJ##0b, env0a, env0b, es, zp);              \
    short8 afr1 = mk_frag(ADJ##1a, ADJ##1b, env1a, env1b, es, zp);              \
    short8 afr2 = mk_frag(ADJ##2a, ADJ##2b, env2a, env2b, es, zp);              \
    short8 afr3 = mk_frag(ADJ##3a, ADJ##3b, env3a, env3b, es, zp);              \
    if ((tt) < 63) {                                                            \
      const float* np = nptr + (size_t)((tt) + 1) * 128;                        \
      env0a = *(const float4*)(np);      env0b = *(const float4*)(np + 4);      \
      env1a = *(const float4*)(np + 32); env1b = *(const float4*)(np + 36);     \
      env2a = *(const float4*)(np + 64); env2b = *(const float4*)(np + 68);     \
      env3a = *(const float4*)(np + 96); env3b = *(const float4*)(np + 100);    \
    }                                                                           \
    if ((tt) < 62) {                                                            \
      const int* ap = aptr + (size_t)((tt) + 2) * 128;                          \
      ADJ##0a = *(const int4*)(ap);       ADJ##0b = *(const int4*)(ap + 4);     \
      ADJ##1a = *(const int4*)(ap + 32);  ADJ##1b = *(const int4*)(ap + 36);    \
      ADJ##2a = *(const int4*)(ap + 64);  ADJ##2b = *(const int4*)(ap + 68);    \
      ADJ##3a = *(const int4*)(ap + 96);  ADJ##3b = *(const int4*)(ap + 100);   \
    }                                                                           \
    acc0 = __builtin_amdgcn_mfma_f32_16x16x32_bf16(afr0, b0.s, acc0, 0, 0, 0);  \
    acc1 = __builtin_amdgcn_mfma_f32_16x16x32_bf16(afr0, b4.s, acc1, 0, 0, 0);  \
    acc0 = __builtin_amdgcn_mfma_f32_16x16x32_bf16(afr1, b1.s, acc0, 0, 0, 0);  \
    acc1 = __builtin_amdgcn_mfma_f32_16x16x32_bf16(afr1, b5.s, acc1, 0, 0, 0);  \
    acc0 = __builtin_amdgcn_mfma_f32_16x16x32_bf16(afr2, b2.s, acc0, 0, 0, 0);  \
    acc1 = __builtin_amdgcn_mfma_f32_16x16x32_bf16(afr2, b6.s, acc1, 0, 0, 0);  \
    acc0 = __builtin_amdgcn_mfma_f32_16x16x32_bf16(afr3, b3.s, acc0, 0, 0, 0);  \
    acc1 = __builtin_amdgcn_mfma_f32_16x16x32_bf16(afr3, b7.s, acc1, 0, 0, 0);  \
    if ((tt) < 63) {                                                            \
      const size_t jt = (size_t)((tt) + 1) * 128;                               \
      b0.u = *(const uint4*)(bb0 + jt);      b1.u = *(const uint4*)(bb0 + jt + 32); \
      b2.u = *(const uint4*)(bb0 + jt + 64); b3.u = *(const uint4*)(bb0 + jt + 96); \
      b4.u = *(const uint4*)(bb1 + jt);      b5.u = *(const uint4*)(bb1 + jt + 32); \
      b6.u = *(const uint4*)(bb1 + jt + 64); b7.u = *(const uint4*)(bb1 + jt + 96); \
    }                                                                           \
  }

__global__ __launch_bounds__(256)
__attribute__((amdgpu_waves_per_eu(2, 2)))
void k_main(const int* __restrict__ A,
            const unsigned short* __restrict__ HnT,
            const float* __restrict__ es_g,
            const float* __restrict__ en_g,
            float* __restrict__ HsOut) {
  const int t = threadIdx.x;
  const int wv = t >> 6;
  const int ln = t & 63;
  const int q = ln >> 4;   // quad
  const int m = ln & 15;   // A row / C col
  const int row0 = blockIdx.x * 16;

  const float es = es_g[row0 + m];
  const int* aptr = A + (size_t)(row0 + m) * NN + q * 8;
  const float* nptr = en_g + q * 8;
  const int f0 = wv * 32 + m;
  const unsigned short* bb0 = HnT + (size_t)f0 * NN + q * 8;
  const unsigned short* bb1 = HnT + (size_t)(f0 + 16) * NN + q * 8;

  f32x4 acc0 = {0.f, 0.f, 0.f, 0.f}, acc1 = {0.f, 0.f, 0.f, 0.f};
  float zp = 0.f;

  // named prefetch registers (even tiles = A-set, odd tiles = B-set for adj)
  int4 adjA0a, adjA0b, adjA1a, adjA1b, adjA2a, adjA2b, adjA3a, adjA3b;
  int4 adjB0a, adjB0b, adjB1a, adjB1b, adjB2a, adjB2b, adjB3a, adjB3b;
  float4 env0a, env0b, env1a, env1b, env2a, env2b, env3a, env3b;  // single set
  union BU { uint4 u; short8 s; } b0, b1, b2, b3, b4, b5, b6, b7;

  // prolog (FIFO oldest-first): env(0), adj(0), adj(1), B(0)
  env0a = *(const float4*)(nptr);      env0b = *(const float4*)(nptr + 4);
  env1a = *(const float4*)(nptr + 32); env1b = *(const float4*)(nptr + 36);
  env2a = *(const float4*)(nptr + 64); env2b = *(const float4*)(nptr + 68);
  env3a = *(const float4*)(nptr + 96); env3b = *(const float4*)(nptr + 100);
  adjA0a = *(const int4*)(aptr);       adjA0b = *(const int4*)(aptr + 4);
  adjA1a = *(const int4*)(aptr + 32);  adjA1b = *(const int4*)(aptr + 36);
  adjA2a = *(const int4*)(aptr + 64);  adjA2b = *(const int4*)(aptr + 68);
  adjA3a = *(const int4*)(aptr + 96);  adjA3b = *(const int4*)(aptr + 100);
  adjB0a = *(const int4*)(aptr + 128);  adjB0b = *(const int4*)(aptr + 132);
  adjB1a = *(const int4*)(aptr + 160);  adjB1b = *(const int4*)(aptr + 164);
  adjB2a = *(const int4*)(aptr + 192);  adjB2b = *(const int4*)(aptr + 196);
  adjB3a = *(const int4*)(aptr + 224);  adjB3b = *(const int4*)(aptr + 228);
  b0.u = *(const uint4*)(bb0);      b1.u = *(const uint4*)(bb0 + 32);
  b2.u = *(const uint4*)(bb0 + 64); b3.u = *(const uint4*)(bb0 + 96);
  b4.u = *(const uint4*)(bb1);      b5.u = *(const uint4*)(bb1 + 32);
  b6.u = *(const uint4*)(bb1 + 64); b7.u = *(const uint4*)(bb1 + 96);

  for (int tt = 0; tt < 64; tt += 2) {
    GAT_BODY(tt, adjA)
    GAT_BODY(tt + 1, adjB)
  }

  // ---- Z: in-wave butterfly across q (lanes share m at ln = q*16+m) ----
  float zz = zp;
  zz += __shfl_xor(zz, 16);
  zz += __shfl_xor(zz, 32);           // every lane now holds Z[m] for its m
  const float invz = 1.f / zz;

  // ---- epilogue: out = elu(0.5*h_s + acc/Z); C-layout col=m, row=q*4+reg ----
#pragma unroll
  for (int reg = 0; reg < 4; ++reg) {
    const int row = q * 4 + reg;
    const float iz = __shfl(invz, row);  // lane 'row' has m==row
    const size_t off = (size_t)(row0 + row) * 128 + f0;
    float h0 = HsOut[off], h1 = HsOut[off + 16];
    HsOut[off]      = eluf(fmaf(acc0[reg], iz, 0.5f * h0));
    HsOut[off + 16] = eluf(fmaf(acc1[reg], iz, 0.5f * h1));
  }
}

extern "C" void kernel_launch(void* const* d_in, const int* in_sizes, int n_in,
                              void* d_out, int out_size, void* d_ws, size_t ws_size,
                              hipStream_t stream) {
  const float* X   = (const float*)d_in[0];
  const int*   A   = (const int*)d_in[1];
  const float* Ws  = (const float*)d_in[2];
  const float* as_ = (const float*)d_in[3];
  const float* Wn  = (const float*)d_in[4];
  const float* an_ = (const float*)d_in[5];
  float* out = (float*)d_out;  // holds h_s, then final output (in-place epilogue)

  unsigned short* HnT = (unsigned short*)d_ws;       // 128*8192 bf16 = 2 MB
  float* es = (float*)(HnT + (size_t)128 * NN);      // 8192 f32 (= exp(s))
  float* en = es + NN;                               // 8192 f32 (= exp(n))

  k_proj<<<1024, 256, 0, stream>>>(X, Ws, Wn, as_, an_, out, HnT, es, en);
  k_main<<<512, 256, 0, stream>>>(A, HnT, es, en, out);
}

// Round 7
// 524.105 us; speedup vs baseline: 1.4978x; 1.0734x over previous
//
#include <hip/hip_runtime.h>
#include <hip/hip_bf16.h>
#include <math.h>

#define NN 8192
// out = elu(0.5*h_s + (sum_j w_ij h_n_j)/Z_i), w_ij = adj_ij * max(es_i*en_j, 1)
// es = exp(s), en = exp(n): exp(relu(s+n)) == max(exp(s)*exp(n), 1)

typedef short short8 __attribute__((ext_vector_type(8)));   // 8 bf16 (4 VGPRs)
typedef float f32x4 __attribute__((ext_vector_type(4)));

__device__ __forceinline__ float eluf(float x) {
  return x > 0.f ? x : (__expf(x) - 1.f);
}
__device__ __forceinline__ unsigned short f2bf(float f) {
  union { float f; unsigned u; } v; v.f = f;
  unsigned r = v.u + 0x7fffu + ((v.u >> 16) & 1u);  // RNE
  return (unsigned short)(r >> 16);
}

// ---------------- Kernel 0: adj (268 MB int32) -> bitmask (8 MB) ----------------
// Pure HBM stream. 1024 blocks x 256 thr = 262144 threads; 8 uints each.
// uint u, bit b  <->  adj flat element u*32+b  (rows divide evenly: 8192%32==0)
__global__ __launch_bounds__(256) void k_mask(const int* __restrict__ A,
                                              unsigned* __restrict__ M) {
  const int gt = blockIdx.x * 256 + threadIdx.x;
  const int TOT = 1024 * 256;
  for (int it = 0; it < 8; ++it) {
    const size_t u = (size_t)it * TOT + gt;
    const int4* p = (const int4*)(A + u * 32);
    unsigned msk = 0;
#pragma unroll
    for (int k = 0; k < 8; ++k) {
      int4 v = p[k];
      msk |= (unsigned)(v.x > 0) << (k * 4 + 0);
      msk |= (unsigned)(v.y > 0) << (k * 4 + 1);
      msk |= (unsigned)(v.z > 0) << (k * 4 + 2);
      msk |= (unsigned)(v.w > 0) << (k * 4 + 3);
    }
    M[u] = msk;
  }
}

// ---------------- Kernel 1: projections + fused exp(s)/exp(n) reductions ----------------
// 8 rows/block, block 256, grid 1024
__global__ __launch_bounds__(256) void k_proj(const float* __restrict__ X,
                                              const float* __restrict__ Ws,
                                              const float* __restrict__ Wn,
                                              const float* __restrict__ as_,
                                              const float* __restrict__ an_,
                                              float* __restrict__ Hs,
                                              unsigned short* __restrict__ HnT,
                                              float* __restrict__ es_out,
                                              float* __restrict__ en_out) {
  __shared__ float4 lin4[8 * 64];  // 8 rows x 256 f32 = 8 KB
  const int t = threadIdx.x;
  const int i0 = blockIdx.x * 8;
  const float4* Xg = (const float4*)X + (size_t)i0 * 64;
  lin4[t] = Xg[t];
  if (t < 256) lin4[t + 256] = Xg[t + 256];
  __syncthreads();
  const int c = t & 127;
  const int rh = t >> 7;  // 0..1, 4 rows each
  float accs[4], accn[4];
#pragma unroll
  for (int r = 0; r < 4; ++r) { accs[r] = 0.f; accn[r] = 0.f; }
  for (int k = 0; k < 256; k += 4) {
    float ws0 = Ws[(k + 0) * 128 + c], ws1 = Ws[(k + 1) * 128 + c];
    float ws2 = Ws[(k + 2) * 128 + c], ws3 = Ws[(k + 3) * 128 + c];
    float wn0 = Wn[(k + 0) * 128 + c], wn1 = Wn[(k + 1) * 128 + c];
    float wn2 = Wn[(k + 2) * 128 + c], wn3 = Wn[(k + 3) * 128 + c];
#pragma unroll
    for (int r = 0; r < 4; ++r) {
      float4 iv = lin4[(rh * 4 + r) * 64 + (k >> 2)];  // wave-uniform broadcast
      accs[r] = fmaf(iv.x, ws0, accs[r]); accs[r] = fmaf(iv.y, ws1, accs[r]);
      accs[r] = fmaf(iv.z, ws2, accs[r]); accs[r] = fmaf(iv.w, ws3, accs[r]);
      accn[r] = fmaf(iv.x, wn0, accn[r]); accn[r] = fmaf(iv.y, wn1, accn[r]);
      accn[r] = fmaf(iv.z, wn2, accn[r]); accn[r] = fmaf(iv.w, wn3, accn[r]);
    }
  }
#pragma unroll
  for (int r = 0; r < 4; ++r)
    Hs[(size_t)(i0 + rh * 4 + r) * 128 + c] = accs[r];
  {
    union { unsigned short us[4]; ushort4 u4; } pk;
#pragma unroll
    for (int r = 0; r < 4; ++r) pk.us[r] = f2bf(accn[r]);
    *(ushort4*)(HnT + (size_t)c * NN + i0 + rh * 4) = pk.u4;
  }
  // ---- fused reductions -> exp ----
  float* red = (float*)lin4;  // 8 x 128 f32
  const int wv = t >> 6, ln = t & 63;
  __syncthreads();
  {
    float av = as_[c];
#pragma unroll
    for (int r = 0; r < 4; ++r) red[(rh * 4 + r) * 128 + c] = accs[r] * av;
  }
  __syncthreads();
#pragma unroll
  for (int h = 0; h < 2; ++h) {
    int row = wv * 2 + h;
    float p = red[row * 128 + ln] + red[row * 128 + 64 + ln];
#pragma unroll
    for (int off = 32; off >= 1; off >>= 1) p += __shfl_down(p, off);
    if (ln == 0) es_out[i0 + row] = __expf(p);
  }
  __syncthreads();
  {
    float av = an_[c];
#pragma unroll
    for (int r = 0; r < 4; ++r) red[(rh * 4 + r) * 128 + c] = accn[r] * av;
  }
  __syncthreads();
#pragma unroll
  for (int h = 0; h < 2; ++h) {
    int row = wv * 2 + h;
    float p = red[row * 128 + ln] + red[row * 128 + 64 + ln];
#pragma unroll
    for (int off = 32; off >= 1; off >>= 1) p += __shfl_down(p, off);
    if (ln == 0) en_out[i0 + row] = __expf(p);
  }
}

// ---------------- Kernel 2: fused attention GEMM from bitmask ----------------
// 32 rows/block, 512 threads (8 waves), grid 256. j-tiles of 128 (64 tiles).
// K-slice -> j mapping: j = tt*128 + q*32 + ks*8 + jj (valid bijection per mfma,
// used consistently for A-frags, B-frags, en and the mask) -> each lane's mask
// for a whole tile is ONE uint. Mask slab + en live in LDS; only B comes from
// global (L2-resident HnT, depth-1 register prefetch). No barrier in the loop.

__device__ __forceinline__ short8 mk_frag(unsigned mu, int sh, float4 ea, float4 eb,
                                          float es, float& zp) {
  float w0 = (mu >> (sh + 0)) & 1u ? fmaxf(es * ea.x, 1.f) : 0.f;
  float w1 = (mu >> (sh + 1)) & 1u ? fmaxf(es * ea.y, 1.f) : 0.f;
  float w2 = (mu >> (sh + 2)) & 1u ? fmaxf(es * ea.z, 1.f) : 0.f;
  float w3 = (mu >> (sh + 3)) & 1u ? fmaxf(es * ea.w, 1.f) : 0.f;
  float w4 = (mu >> (sh + 4)) & 1u ? fmaxf(es * eb.x, 1.f) : 0.f;
  float w5 = (mu >> (sh + 5)) & 1u ? fmaxf(es * eb.y, 1.f) : 0.f;
  float w6 = (mu >> (sh + 6)) & 1u ? fmaxf(es * eb.z, 1.f) : 0.f;
  float w7 = (mu >> (sh + 7)) & 1u ? fmaxf(es * eb.w, 1.f) : 0.f;
  zp += ((w0 + w1) + (w2 + w3)) + ((w4 + w5) + (w6 + w7));
  __hip_bfloat162 p01 = __float22bfloat162_rn(float2{w0, w1});
  __hip_bfloat162 p23 = __float22bfloat162_rn(float2{w2, w3});
  __hip_bfloat162 p45 = __float22bfloat162_rn(float2{w4, w5});
  __hip_bfloat162 p67 = __float22bfloat162_rn(float2{w6, w7});
  union { unsigned u[4]; short8 s; } fr;
  fr.u[0] = *(unsigned*)&p01; fr.u[1] = *(unsigned*)&p23;
  fr.u[2] = *(unsigned*)&p45; fr.u[3] = *(unsigned*)&p67;
  return fr.s;
}

#define MFMA_BF16 __builtin_amdgcn_mfma_f32_16x16x32_bf16

#define GAT_BODY(tt, MU)                                                          \
  {                                                                               \
    const int jt = (tt) * 128;                                                    \
    float4 e0a = *(const float4*)(envp + jt);      float4 e0b = *(const float4*)(envp + jt + 4);  \
    float4 e1a = *(const float4*)(envp + jt + 8);  float4 e1b = *(const float4*)(envp + jt + 12); \
    float4 e2a = *(const float4*)(envp + jt + 16); float4 e2b = *(const float4*)(envp + jt + 20); \
    float4 e3a = *(const float4*)(envp + jt + 24); float4 e3b = *(const float4*)(envp + jt + 28); \
    short8 afr0 = mk_frag(MU, 0, e0a, e0b, es, zp);                               \
    short8 afr1 = mk_frag(MU, 8, e1a, e1b, es, zp);                               \
    short8 afr2 = mk_frag(MU, 16, e2a, e2b, es, zp);                              \
    short8 afr3 = mk_frag(MU, 24, e3a, e3b, es, zp);                              \
    if ((tt) < 62) MU = mrow_p[((tt) + 2) * 4];                                   \
    acc0 = MFMA_BF16(afr0, b0.s, acc0, 0, 0, 0);                                  \
    acc1 = MFMA_BF16(afr0, b4.s, acc1, 0, 0, 0);                                  \
    acc0 = MFMA_BF16(afr1, b1.s, acc0, 0, 0, 0);                                  \
    acc1 = MFMA_BF16(afr1, b5.s, acc1, 0, 0, 0);                                  \
    acc0 = MFMA_BF16(afr2, b2.s, acc0, 0, 0, 0);                                  \
    acc1 = MFMA_BF16(afr2, b6.s, acc1, 0, 0, 0);                                  \
    acc0 = MFMA_BF16(afr3, b3.s, acc0, 0, 0, 0);                                  \
    acc1 = MFMA_BF16(afr3, b7.s, acc1, 0, 0, 0);                                  \
    if ((tt) < 63) {                                                              \
      const int jn = jt + 128;                                                    \
      b0.u = *(const uint4*)(bb0 + jn);      b1.u = *(const uint4*)(bb0 + jn + 8);  \
      b2.u = *(const uint4*)(bb0 + jn + 16); b3.u = *(const uint4*)(bb0 + jn + 24); \
      b4.u = *(const uint4*)(bb1 + jn);      b5.u = *(const uint4*)(bb1 + jn + 8);  \
      b6.u = *(const uint4*)(bb1 + jn + 16); b7.u = *(const uint4*)(bb1 + jn + 24); \
    }                                                                             \
  }

__global__ __launch_bounds__(512) void k_main(const unsigned* __restrict__ Msk,
                                              const unsigned short* __restrict__ HnT,
                                              const float* __restrict__ es_g,
                                              const float* __restrict__ en_g,
                                              float* __restrict__ HsOut) {
  __shared__ float enL[NN];              // 32 KB: exp(n) for all j
  __shared__ unsigned maskL[32 * 257];   // 32.9 KB: 32 rows x 256 uints, +1 pad

  const int t = threadIdx.x;
  const int wv = t >> 6;     // 0..7
  const int ln = t & 63;
  const int q = ln >> 4;     // quad
  const int m = ln & 15;
  const int rh = wv >> 2;    // row half (0..1)
  const int fw = wv & 3;     // f-group (0..3)
  const int row0 = blockIdx.x * 32;
  const int mrow = rh * 16 + m;  // local row 0..31

  // ---- preload en ----
  {
    const float4* eg = (const float4*)en_g;
    float4* el = (float4*)enL;
#pragma unroll
    for (int i = 0; i < 4; ++i) el[t + 512 * i] = eg[t + 512 * i];
  }
  // ---- preload mask slab (coalesced: 16 threads per row) ----
  {
    const int r = t >> 4, c0 = (t & 15) * 16;
    const uint4* mg = (const uint4*)(Msk + (size_t)(row0 + r) * 256 + c0);
    unsigned* d = &maskL[r * 257 + c0];
#pragma unroll
    for (int k = 0; k < 4; ++k) {
      uint4 v = mg[k];
      d[k * 4 + 0] = v.x; d[k * 4 + 1] = v.y; d[k * 4 + 2] = v.z; d[k * 4 + 3] = v.w;
    }
  }
  __syncthreads();

  const float es = es_g[row0 + mrow];
  const int f0 = fw * 32 + m;
  const unsigned short* bb0 = HnT + (size_t)f0 * NN + q * 32;
  const unsigned short* bb1 = HnT + (size_t)(f0 + 16) * NN + q * 32;
  const unsigned* mrow_p = &maskL[mrow * 257 + q];
  const float* envp = enL + q * 32;

  f32x4 acc0 = {0.f, 0.f, 0.f, 0.f}, acc1 = {0.f, 0.f, 0.f, 0.f};
  float zp = 0.f;

  unsigned muA = mrow_p[0];
  unsigned muB = mrow_p[4];
  union BU { uint4 u; short8 s; } b0, b1, b2, b3, b4, b5, b6, b7;
  b0.u = *(const uint4*)(bb0);      b1.u = *(const uint4*)(bb0 + 8);
  b2.u = *(const uint4*)(bb0 + 16); b3.u = *(const uint4*)(bb0 + 24);
  b4.u = *(const uint4*)(bb1);      b5.u = *(const uint4*)(bb1 + 8);
  b6.u = *(const uint4*)(bb1 + 16); b7.u = *(const uint4*)(bb1 + 24);

  for (int tt = 0; tt < 64; tt += 2) {
    GAT_BODY(tt, muA)
    GAT_BODY(tt + 1, muB)
  }

  // ---- Z: in-wave butterfly across q (lanes share m at ln = q*16+m) ----
  float zz = zp;
  zz += __shfl_xor(zz, 16);
  zz += __shfl_xor(zz, 32);           // every lane holds Z for its mrow
  const float invz = 1.f / zz;

  // ---- epilogue: out = elu(0.5*h_s + acc/Z); C-layout col=m, row=q*4+reg ----
#pragma unroll
  for (int reg = 0; reg < 4; ++reg) {
    const int r16 = q * 4 + reg;
    const float iz = __shfl(invz, r16);  // lane r16 (q=0,m=r16) holds Z[rh*16+r16]
    const size_t off = (size_t)(row0 + rh * 16 + r16) * 128 + f0;
    float h0 = HsOut[off], h1 = HsOut[off + 16];
    HsOut[off]      = eluf(fmaf(acc0[reg], iz, 0.5f * h0));
    HsOut[off + 16] = eluf(fmaf(acc1[reg], iz, 0.5f * h1));
  }
}

extern "C" void kernel_launch(void* const* d_in, const int* in_sizes, int n_in,
                              void* d_out, int out_size, void* d_ws, size_t ws_size,
                              hipStream_t stream) {
  const float* X   = (const float*)d_in[0];
  const int*   A   = (const int*)d_in[1];
  const float* Ws  = (const float*)d_in[2];
  const float* as_ = (const float*)d_in[3];
  const float* Wn  = (const float*)d_in[4];
  const float* an_ = (const float*)d_in[5];
  float* out = (float*)d_out;  // holds h_s, then final output (in-place epilogue)

  // workspace: HnT 2 MB | es 32 KB | en 32 KB | mask 8 MB  (~10.1 MB total)
  unsigned short* HnT = (unsigned short*)d_ws;
  float* es = (float*)(HnT + (size_t)128 * NN);
  float* en = es + NN;
  unsigned* Msk = (unsigned*)(en + NN);

  k_mask<<<1024, 256, 0, stream>>>(A, Msk);
  k_proj<<<1024, 256, 0, stream>>>(X, Ws, Wn, as_, an_, out, HnT, es, en);
  k_main<<<256, 512, 0, stream>>>(Msk, HnT, es, en, out);
}